// Round 4
// baseline (352.976 us; speedup 1.0000x reference)
//
#include <hip/hip_runtime.h>
#include <math.h>

#define BB 8
#define MI 16
#define NN 409600          // 640*640
#define CEPS 1e-12f
#define GPB 200            // blocks per image; 2048 px/block, 8 px/thread
#define TPB 256

// ws float layout — no zero-init needed (every slot written before read):
//   PS:  k_sums partials [b][v][blk], v = id*5+c (c<4 channel sums, c=4 count)
//   G:   [b][m][4]  (float4 aligned)
//   VAL: [b][m]
//   PP:  k_pull partials [b][v][blk], v = id*2+c (c=0 loss sum, c=1 count)
#define WS_PS   0
#define WS_G    (BB*80*GPB)            // 128000
#define WS_VAL  (WS_G + BB*MI*4)
#define WS_PP   (WS_VAL + BB*MI)

// Bank-replicated LDS histogram: word index (v*32 + lane&31) => bank == lane&31.
// Each 32-lane LDS phase: all distinct banks, all distinct addresses => full rate.

__global__ __launch_bounds__(TPB) void k_sums(
    const float* __restrict__ outputs, const int* __restrict__ gt_kernels,
    float* __restrict__ ws) {
  __shared__ float hist[MI * 5 * 32];   // 10 KB: (id*5+c)*32 + r
  const int b = blockIdx.y, blk = blockIdx.x, tid = threadIdx.x;
  for (int i = tid; i < MI * 5 * 32; i += TPB) hist[i] = 0.f;
  __syncthreads();

  const float* s0 = outputs + (size_t)(b * 8 + 4) * NN;
  const int* gkb = gt_kernels + (size_t)b * NN;
  const int r = tid & 31;

#pragma unroll
  for (int c = 0; c < 2; c++) {
    const int pix = blk * 2048 + c * 1024 + tid * 4;
    const int4 id4 = *(const int4*)(gkb + pix);
    const float4 x0 = *(const float4*)(s0 + pix);
    const float4 x1 = *(const float4*)(s0 + NN + pix);
    const float4 x2 = *(const float4*)(s0 + 2 * NN + pix);
    const float4 x3 = *(const float4*)(s0 + 3 * NN + pix);
#define SLOTK(IDC, XC)                                                       \
    {                                                                        \
      float* h = &hist[id4.IDC * 160 + r];   /* (id*5+0)*32 + r */           \
      atomicAdd(h + 0,   x0.XC);                                             \
      atomicAdd(h + 32,  x1.XC);                                             \
      atomicAdd(h + 64,  x2.XC);                                             \
      atomicAdd(h + 96,  x3.XC);                                             \
      atomicAdd(h + 128, 1.f);                                               \
    }
    SLOTK(x, x) SLOTK(y, y) SLOTK(z, z) SLOTK(w, w)
#undef SLOTK
  }
  __syncthreads();

  // reduce 32 replicas per (id,c); skewed reads avoid bank conflicts
  if (tid < 80) {
    float s = 0.f;
#pragma unroll
    for (int k = 0; k < 32; k++) s += hist[tid * 32 + ((k + tid) & 31)];
    ws[WS_PS + (b * 80 + tid) * GPB + blk] = s;
  }
}

__global__ void k_finG(float* __restrict__ ws) {
  __shared__ float part[4][80];
  __shared__ float tot[80];
  const int b = blockIdx.x, t = threadIdx.x;   // 320 threads
  const int v = t % 80, h = t / 80;            // h < 4, 50 partials each
  float s = 0.f;
  const float* src = ws + WS_PS + (b * 80 + v) * GPB + h * 50;
#pragma unroll 5
  for (int k = 0; k < 50; k++) s += src[k];
  part[h][v] = s;
  __syncthreads();
  if (t < 80) tot[t] = part[0][t] + part[1][t] + part[2][t] + part[3][t];
  __syncthreads();
  if (t < MI) {
    const float cnt = tot[t * 5 + 4];
    const float inv = 1.f / fmaxf(cnt, 1.f);
    float4 g;
    g.x = tot[t * 5 + 0] * inv;
    g.y = tot[t * 5 + 1] * inv;
    g.z = tot[t * 5 + 2] * inv;
    g.w = tot[t * 5 + 3] * inv;
    ((float4*)(ws + WS_G))[b * MI + t] = g;
    ws[WS_VAL + b * MI + t] = (cnt > 0.f && t >= 1) ? 1.f : 0.f;
  }
}

__global__ __launch_bounds__(TPB) void k_pull(
    const float* __restrict__ outputs, const int* __restrict__ gt_texts,
    float* __restrict__ ws) {
  __shared__ float hist[MI * 2 * 32];   // 4 KB: (id*2+c)*32 + r
  __shared__ float4 sG[MI];
  const int b = blockIdx.y, blk = blockIdx.x, tid = threadIdx.x;
  for (int i = tid; i < MI * 2 * 32; i += TPB) hist[i] = 0.f;
  if (tid < MI) sG[tid] = ((const float4*)(ws + WS_G))[b * MI + tid];
  __syncthreads();

  const float* s0 = outputs + (size_t)(b * 8 + 4) * NN;
  const int* ttb = gt_texts + (size_t)b * NN;
  const int r = tid & 31;

#pragma unroll
  for (int c = 0; c < 2; c++) {
    const int pix = blk * 2048 + c * 1024 + tid * 4;
    const int4 id4 = *(const int4*)(ttb + pix);
    const float4 x0 = *(const float4*)(s0 + pix);
    const float4 x1 = *(const float4*)(s0 + NN + pix);
    const float4 x2 = *(const float4*)(s0 + 2 * NN + pix);
    const float4 x3 = *(const float4*)(s0 + 3 * NN + pix);
#define SLOTP(IDC, XC)                                                       \
    {                                                                        \
      const int id = id4.IDC;                                                \
      const float4 g = sG[id];                                               \
      const float d0 = x0.XC - g.x, d1 = x1.XC - g.y;                        \
      const float d2 = x2.XC - g.z, d3 = x3.XC - g.w;                        \
      const float dist = sqrtf(d0*d0 + d1*d1 + d2*d2 + d3*d3 + CEPS) - 0.5f; \
      const float dm = fmaxf(dist, 0.f);                                     \
      const float l = __logf(1.f + dm * dm);                                 \
      float* h = &hist[id * 64 + r];                                         \
      atomicAdd(h + 0,  l);                                                  \
      atomicAdd(h + 32, 1.f);                                                \
    }
    SLOTP(x, x) SLOTP(y, y) SLOTP(z, z) SLOTP(w, w)
#undef SLOTP
  }
  __syncthreads();

  if (tid < 32) {
    float s = 0.f;
#pragma unroll
    for (int k = 0; k < 32; k++) s += hist[tid * 32 + ((k + tid) & 31)];
    ws[WS_PP + (b * 32 + tid) * GPB + blk] = s;
  }
}

__global__ void k_final(const float* __restrict__ ws, float* __restrict__ out) {
  __shared__ float tot[256];                  // [b][v], v = m*2+c
  const int t = threadIdx.x;                  // 256 threads
  const int b = t >> 5, v = t & 31;
  float s = 0.f;
  const float* src = ws + WS_PP + (b * 32 + v) * GPB;
#pragma unroll 4
  for (int k = 0; k < GPB; k++) s += src[k];
  tot[t] = s;
  __syncthreads();
  if (t < BB) {
    const int bb = t;
    const float* G = ws + WS_G;
    const float* valid = ws + WS_VAL;
    float nv = 0.f;
    for (int m = 0; m < MI; m++) nv += valid[bb * MI + m];
    float pull = 0.f;
    for (int m = 0; m < MI; m++) {
      const float per = tot[bb * 32 + m * 2] / fmaxf(tot[bb * 32 + m * 2 + 1], 1.f);
      pull += per * valid[bb * MI + m];
    }
    pull /= fmaxf(nv, 1.f);
    float push = 0.f;
    for (int i = 0; i < MI; i++) {
      if (valid[bb * MI + i] == 0.f) continue;
      for (int j = i + 1; j < MI; j++) {
        if (valid[bb * MI + j] == 0.f) continue;
        float d2 = CEPS;
        for (int c = 0; c < 4; c++) {
          const float df = G[(bb * MI + i) * 4 + c] - G[(bb * MI + j) * 4 + c];
          d2 += df * df;
        }
        const float dk = sqrtf(d2);
        const float tt = fmaxf(3.f - dk, 0.f);
        push += log1pf(tt * tt);
      }
    }
    const float denom = nv * (nv - 1.f);
    push = (nv > 1.f) ? push / fmaxf(denom, 1.f) : 0.f;
    out[bb] = pull;
    out[BB + bb] = push;
  }
}

extern "C" void kernel_launch(void* const* d_in, const int* in_sizes, int n_in,
                              void* d_out, int out_size, void* d_ws, size_t ws_size,
                              hipStream_t stream) {
  const float* outputs = (const float*)d_in[0];
  const int* gt_texts = (const int*)d_in[1];
  const int* gt_kernels = (const int*)d_in[2];
  float* ws = (float*)d_ws;
  float* out = (float*)d_out;

  dim3 grid(GPB, BB);
  k_sums<<<grid, TPB, 0, stream>>>(outputs, gt_kernels, ws);
  k_finG<<<BB, 320, 0, stream>>>(ws);
  k_pull<<<grid, TPB, 0, stream>>>(outputs, gt_texts, ws);
  k_final<<<1, 256, 0, stream>>>(ws, out);
}

// Round 5
// 270.754 us; speedup vs baseline: 1.3037x; 1.3037x over previous
//
#include <hip/hip_runtime.h>
#include <math.h>

#define BB 8
#define MI 16
#define NN 409600          // 640*640
#define CEPS 1e-12f
#define GPB 200            // blocks per image; 2048 px/block
#define TPB 256

// ws float layout — no zero-init needed (every slot written before read):
//   PS:  k_sums partials [b][v][blk], v = m*5+c (c<4 channel sums, c=4 count)
//   G:   [b][m][4]  (float4 aligned)
//   VAL: [b][m]
//   PP:  k_pull partials [b][v][blk], v = m*2+c (c=0 loss sum, c=1 count)
#define WS_PS   0
#define WS_G    (BB*80*GPB)            // 128000
#define WS_VAL  (WS_G + BB*MI*4)
#define WS_PP   (WS_VAL + BB*MI)

// k_sums: wave w owns ids 4w..4w+3 (16 acc VGPRs). Every wave streams the
// whole 2048-px chunk (redundant reads are L1/L2-absorbed). Counts on the
// scalar pipe via ballot+popc. No atomics anywhere.
__global__ __launch_bounds__(TPB, 6) void k_sums(
    const float* __restrict__ outputs, const int* __restrict__ gt_kernels,
    float* __restrict__ ws) {
  __shared__ float red[4][64][17];     // stride-17: conflict-free columns
  __shared__ float cbuf[MI];
  const int b = blockIdx.y, blk = blockIdx.x, tid = threadIdx.x;
  const int wv = tid >> 6, lane = tid & 63;
  const int mb = wv * 4;

  float acc[16];                       // acc[c*4+j]: channel c, id mb+j
#pragma unroll
  for (int i = 0; i < 16; i++) acc[i] = 0.f;
  unsigned int cnt[4] = {0u, 0u, 0u, 0u};

  const float* s0 = outputs + (size_t)(b * 8 + 4) * NN;
  const int* gkb = gt_kernels + (size_t)b * NN;

#pragma unroll 2
  for (int it = 0; it < 8; it++) {
    const int pix = blk * 2048 + it * 256 + lane * 4;
    const int4 id4 = *(const int4*)(gkb + pix);
    const float4 x0 = *(const float4*)(s0 + pix);
    const float4 x1 = *(const float4*)(s0 + NN + pix);
    const float4 x2 = *(const float4*)(s0 + 2 * NN + pix);
    const float4 x3 = *(const float4*)(s0 + 3 * NN + pix);
#define SLOTK(IDC, XC)                                                       \
    {                                                                        \
      const int id = id4.IDC - mb;                                           \
      _Pragma("unroll")                                                      \
      for (int j = 0; j < 4; j++) {                                          \
        const bool e = (id == j);                                            \
        cnt[j] += (unsigned)__popcll(__ballot(e));   /* scalar pipe */       \
        const float f = e ? 1.f : 0.f;                                       \
        acc[0 * 4 + j] += f * x0.XC;                                         \
        acc[1 * 4 + j] += f * x1.XC;                                         \
        acc[2 * 4 + j] += f * x2.XC;                                         \
        acc[3 * 4 + j] += f * x3.XC;                                         \
      }                                                                      \
    }
    SLOTK(x, x) SLOTK(y, y) SLOTK(z, z) SLOTK(w, w)
#undef SLOTK
  }

  // flush: per-lane partials -> LDS, then 80 threads reduce 64 lanes each
#pragma unroll
  for (int v = 0; v < 16; v++) red[wv][lane][v] = acc[v];
  if (lane == 0) {
#pragma unroll
    for (int j = 0; j < 4; j++) cbuf[mb + j] = (float)cnt[j];
  }
  __syncthreads();
  if (tid < 80) {
    const int m = tid / 5, c = tid % 5;
    const int w = m >> 2, j = m & 3;
    float s;
    if (c < 4) {
      const int vi = c * 4 + j;
      s = 0.f;
#pragma unroll 8
      for (int l = 0; l < 64; l++) s += red[w][(l + tid) & 63][vi];
    } else {
      s = cbuf[m];
    }
    ws[WS_PS + (b * 80 + tid) * GPB + blk] = s;
  }
}

__global__ void k_finG(float* __restrict__ ws) {
  __shared__ float part[4][80];
  __shared__ float tot[80];
  const int b = blockIdx.x, t = threadIdx.x;   // 320 threads
  const int v = t % 80, h = t / 80;            // h < 4, 50 partials each
  float s = 0.f;
  const float* src = ws + WS_PS + (b * 80 + v) * GPB + h * 50;
#pragma unroll 5
  for (int k = 0; k < 50; k++) s += src[k];
  part[h][v] = s;
  __syncthreads();
  if (t < 80) tot[t] = part[0][t] + part[1][t] + part[2][t] + part[3][t];
  __syncthreads();
  if (t < MI) {
    const float cnt = tot[t * 5 + 4];
    const float inv = 1.f / fmaxf(cnt, 1.f);
    float4 g;
    g.x = tot[t * 5 + 0] * inv;
    g.y = tot[t * 5 + 1] * inv;
    g.z = tot[t * 5 + 2] * inv;
    g.w = tot[t * 5 + 3] * inv;
    ((float4*)(ws + WS_G))[b * MI + t] = g;
    ws[WS_VAL + b * MI + t] = (cnt > 0.f && t >= 1) ? 1.f : 0.f;
  }
}

// k_pull: dist/log once per pixel; al[16] register accumulators (scalar l),
// counts on the scalar pipe. No atomics.
__global__ __launch_bounds__(TPB, 6) void k_pull(
    const float* __restrict__ outputs, const int* __restrict__ gt_texts,
    float* __restrict__ ws) {
  __shared__ float4 sG[MI];
  __shared__ float red[4][64][17];
  __shared__ float cbuf[4][MI];
  const int b = blockIdx.y, blk = blockIdx.x, tid = threadIdx.x;
  const int wv = tid >> 6, lane = tid & 63;
  if (tid < MI) sG[tid] = ((const float4*)(ws + WS_G))[b * MI + tid];
  __syncthreads();

  float al[16];
#pragma unroll
  for (int m = 0; m < MI; m++) al[m] = 0.f;
  unsigned int cw[16];
#pragma unroll
  for (int m = 0; m < MI; m++) cw[m] = 0u;

  const float* s0 = outputs + (size_t)(b * 8 + 4) * NN;
  const int* ttb = gt_texts + (size_t)b * NN;

#pragma unroll
  for (int it = 0; it < 2; it++) {
    const int pix = blk * 2048 + it * 1024 + tid * 4;
    const int4 id4 = *(const int4*)(ttb + pix);
    const float4 x0 = *(const float4*)(s0 + pix);
    const float4 x1 = *(const float4*)(s0 + NN + pix);
    const float4 x2 = *(const float4*)(s0 + 2 * NN + pix);
    const float4 x3 = *(const float4*)(s0 + 3 * NN + pix);
#define SLOTP(IDC, XC)                                                       \
    {                                                                        \
      const int id = id4.IDC;                                                \
      const float4 g = sG[id];                                               \
      const float d0 = x0.XC - g.x, d1 = x1.XC - g.y;                        \
      const float d2 = x2.XC - g.z, d3 = x3.XC - g.w;                        \
      const float dist = sqrtf(d0*d0 + d1*d1 + d2*d2 + d3*d3 + CEPS) - 0.5f; \
      const float dm = fmaxf(dist, 0.f);                                     \
      const float l = __logf(1.f + dm * dm);                                 \
      _Pragma("unroll")                                                      \
      for (int m = 0; m < MI; m++) {                                         \
        const bool e = (id == m);                                            \
        cw[m] += (unsigned)__popcll(__ballot(e));    /* scalar pipe */       \
        al[m] += e ? l : 0.f;                                                \
      }                                                                      \
    }
    SLOTP(x, x) SLOTP(y, y) SLOTP(z, z) SLOTP(w, w)
#undef SLOTP
  }

#pragma unroll
  for (int v = 0; v < 16; v++) red[wv][lane][v] = al[v];
  if (lane == 0) {
#pragma unroll
    for (int m = 0; m < MI; m++) cbuf[wv][m] = (float)cw[m];
  }
  __syncthreads();
  if (tid < 32) {
    const int m = tid >> 1, c = tid & 1;
    float s = 0.f;
    if (c == 0) {
#pragma unroll
      for (int w = 0; w < 4; w++)
#pragma unroll 8
        for (int l = 0; l < 64; l++) s += red[w][(l + tid) & 63][m];
    } else {
      s = cbuf[0][m] + cbuf[1][m] + cbuf[2][m] + cbuf[3][m];
    }
    ws[WS_PP + (b * 32 + tid) * GPB + blk] = s;
  }
}

__global__ void k_final(const float* __restrict__ ws, float* __restrict__ out) {
  __shared__ float tot[256];                  // [b][v], v = m*2+c
  const int t = threadIdx.x;                  // 256 threads
  const int b = t >> 5, v = t & 31;
  float s = 0.f;
  const float* src = ws + WS_PP + (b * 32 + v) * GPB;
#pragma unroll 4
  for (int k = 0; k < GPB; k++) s += src[k];
  tot[t] = s;
  __syncthreads();
  if (t < BB) {
    const int bb = t;
    const float* G = ws + WS_G;
    const float* valid = ws + WS_VAL;
    float nv = 0.f;
    for (int m = 0; m < MI; m++) nv += valid[bb * MI + m];
    float pull = 0.f;
    for (int m = 0; m < MI; m++) {
      const float per = tot[bb * 32 + m * 2] / fmaxf(tot[bb * 32 + m * 2 + 1], 1.f);
      pull += per * valid[bb * MI + m];
    }
    pull /= fmaxf(nv, 1.f);
    float push = 0.f;
    for (int i = 0; i < MI; i++) {
      if (valid[bb * MI + i] == 0.f) continue;
      for (int j = i + 1; j < MI; j++) {
        if (valid[bb * MI + j] == 0.f) continue;
        float d2 = CEPS;
        for (int c = 0; c < 4; c++) {
          const float df = G[(bb * MI + i) * 4 + c] - G[(bb * MI + j) * 4 + c];
          d2 += df * df;
        }
        const float dk = sqrtf(d2);
        const float tt = fmaxf(3.f - dk, 0.f);
        push += log1pf(tt * tt);
      }
    }
    const float denom = nv * (nv - 1.f);
    push = (nv > 1.f) ? push / fmaxf(denom, 1.f) : 0.f;
    out[bb] = pull;
    out[BB + bb] = push;
  }
}

extern "C" void kernel_launch(void* const* d_in, const int* in_sizes, int n_in,
                              void* d_out, int out_size, void* d_ws, size_t ws_size,
                              hipStream_t stream) {
  const float* outputs = (const float*)d_in[0];
  const int* gt_texts = (const int*)d_in[1];
  const int* gt_kernels = (const int*)d_in[2];
  float* ws = (float*)d_ws;
  float* out = (float*)d_out;

  dim3 grid(GPB, BB);
  k_sums<<<grid, TPB, 0, stream>>>(outputs, gt_kernels, ws);
  k_finG<<<BB, 320, 0, stream>>>(ws);
  k_pull<<<grid, TPB, 0, stream>>>(outputs, gt_texts, ws);
  k_final<<<1, 256, 0, stream>>>(ws, out);
}

// Round 6
// 252.264 us; speedup vs baseline: 1.3992x; 1.0733x over previous
//
#include <hip/hip_runtime.h>
#include <math.h>

#define BB 8
#define MI 16
#define NN 409600          // 640*640
#define CEPS 1e-12f
#define GPB 200            // blocks per image; 2048 px/block
#define TPB 256

// ws float layout — no zero-init needed (every slot written before read):
//   PS:  k_sums partials [b][blk][v], v = m*5+c (c<4 channel sums, c=4 count)
//   G:   [b][m][4]  (float4 aligned)
//   VAL: [b][m]
//   PP:  k_pull partials [b][blk][v], v = m*2+c (c=0 loss sum, c=1 count)
#define WS_PS   0
#define WS_G    (BB*GPB*80)            // 128000
#define WS_VAL  (WS_G + BB*MI*4)
#define WS_PP   (WS_VAL + BB*MI)

// k_sums: wave w owns ids 4w..4w+3 (16 acc VGPRs). Every wave streams the
// whole 2048-px chunk (redundant reads are L1/L2-absorbed). Counts on the
// scalar pipe via ballot+popc. No atomics anywhere.
__global__ __launch_bounds__(TPB, 6) void k_sums(
    const float* __restrict__ outputs, const int* __restrict__ gt_kernels,
    float* __restrict__ ws) {
  __shared__ float red[4][64][17];     // stride-17: conflict-free columns
  __shared__ float cbuf[MI];
  const int b = blockIdx.y, blk = blockIdx.x, tid = threadIdx.x;
  const int wv = tid >> 6, lane = tid & 63;
  const int mb = wv * 4;

  float acc[16];                       // acc[c*4+j]: channel c, id mb+j
#pragma unroll
  for (int i = 0; i < 16; i++) acc[i] = 0.f;
  unsigned int cnt[4] = {0u, 0u, 0u, 0u};

  const float* s0 = outputs + (size_t)(b * 8 + 4) * NN;
  const int* gkb = gt_kernels + (size_t)b * NN;

#pragma unroll 2
  for (int it = 0; it < 8; it++) {
    const int pix = blk * 2048 + it * 256 + lane * 4;
    const int4 id4 = *(const int4*)(gkb + pix);
    const float4 x0 = *(const float4*)(s0 + pix);
    const float4 x1 = *(const float4*)(s0 + NN + pix);
    const float4 x2 = *(const float4*)(s0 + 2 * NN + pix);
    const float4 x3 = *(const float4*)(s0 + 3 * NN + pix);
#define SLOTK(IDC, XC)                                                       \
    {                                                                        \
      const int id = id4.IDC - mb;                                           \
      _Pragma("unroll")                                                      \
      for (int j = 0; j < 4; j++) {                                          \
        const bool e = (id == j);                                            \
        cnt[j] += (unsigned)__popcll(__ballot(e));   /* scalar pipe */       \
        const float f = e ? 1.f : 0.f;                                       \
        acc[0 * 4 + j] += f * x0.XC;                                         \
        acc[1 * 4 + j] += f * x1.XC;                                         \
        acc[2 * 4 + j] += f * x2.XC;                                         \
        acc[3 * 4 + j] += f * x3.XC;                                         \
      }                                                                      \
    }
    SLOTK(x, x) SLOTK(y, y) SLOTK(z, z) SLOTK(w, w)
#undef SLOTK
  }

  // flush: per-lane partials -> LDS, then 80 threads reduce 64 lanes each
#pragma unroll
  for (int v = 0; v < 16; v++) red[wv][lane][v] = acc[v];
  if (lane == 0) {
#pragma unroll
    for (int j = 0; j < 4; j++) cbuf[mb + j] = (float)cnt[j];
  }
  __syncthreads();
  if (tid < 80) {
    const int m = tid / 5, c = tid % 5;
    const int w = m >> 2, j = m & 3;
    float s;
    if (c < 4) {
      const int vi = c * 4 + j;
      s = 0.f;
#pragma unroll 8
      for (int l = 0; l < 64; l++) s += red[w][(l + tid) & 63][vi];
    } else {
      s = cbuf[m];
    }
    ws[WS_PS + (size_t)(b * GPB + blk) * 80 + tid] = s;   // contiguous per block
  }
}

__global__ void k_finG(float* __restrict__ ws) {
  __shared__ float part[5][80];
  __shared__ float tot[80];
  const int b = blockIdx.x, t = threadIdx.x;   // 400 threads
  const int v = t % 80, h = t / 80;            // h < 5, 40 blocks each
  float s = 0.f;
  const float* src = ws + WS_PS + (size_t)(b * GPB + h * 40) * 80 + v;
#pragma unroll 8
  for (int k = 0; k < 40; k++) s += src[(size_t)k * 80];
  part[h][v] = s;
  __syncthreads();
  if (t < 80) tot[t] = part[0][t] + part[1][t] + part[2][t] + part[3][t] + part[4][t];
  __syncthreads();
  if (t < MI) {
    const float cnt = tot[t * 5 + 4];
    const float inv = 1.f / fmaxf(cnt, 1.f);
    float4 g;
    g.x = tot[t * 5 + 0] * inv;
    g.y = tot[t * 5 + 1] * inv;
    g.z = tot[t * 5 + 2] * inv;
    g.w = tot[t * 5 + 3] * inv;
    ((float4*)(ws + WS_G))[b * MI + t] = g;
    ws[WS_VAL + b * MI + t] = (cnt > 0.f && t >= 1) ? 1.f : 0.f;
  }
}

// k_pull: dist/log once per pixel; al[16] register accumulators (scalar l),
// counts on the scalar pipe. No atomics.
__global__ __launch_bounds__(TPB, 6) void k_pull(
    const float* __restrict__ outputs, const int* __restrict__ gt_texts,
    float* __restrict__ ws) {
  __shared__ float4 sG[MI];
  __shared__ float red[4][64][17];
  __shared__ float cbuf[4][MI];
  const int b = blockIdx.y, blk = blockIdx.x, tid = threadIdx.x;
  const int wv = tid >> 6, lane = tid & 63;
  if (tid < MI) sG[tid] = ((const float4*)(ws + WS_G))[b * MI + tid];
  __syncthreads();

  float al[16];
#pragma unroll
  for (int m = 0; m < MI; m++) al[m] = 0.f;
  unsigned int cw[16];
#pragma unroll
  for (int m = 0; m < MI; m++) cw[m] = 0u;

  const float* s0 = outputs + (size_t)(b * 8 + 4) * NN;
  const int* ttb = gt_texts + (size_t)b * NN;

#pragma unroll
  for (int it = 0; it < 2; it++) {
    const int pix = blk * 2048 + it * 1024 + tid * 4;
    const int4 id4 = *(const int4*)(ttb + pix);
    const float4 x0 = *(const float4*)(s0 + pix);
    const float4 x1 = *(const float4*)(s0 + NN + pix);
    const float4 x2 = *(const float4*)(s0 + 2 * NN + pix);
    const float4 x3 = *(const float4*)(s0 + 3 * NN + pix);
#define SLOTP(IDC, XC)                                                       \
    {                                                                        \
      const int id = id4.IDC;                                                \
      const float4 g = sG[id];                                               \
      const float d0 = x0.XC - g.x, d1 = x1.XC - g.y;                        \
      const float d2 = x2.XC - g.z, d3 = x3.XC - g.w;                        \
      const float dist = sqrtf(d0*d0 + d1*d1 + d2*d2 + d3*d3 + CEPS) - 0.5f; \
      const float dm = fmaxf(dist, 0.f);                                     \
      const float l = __logf(1.f + dm * dm);                                 \
      _Pragma("unroll")                                                      \
      for (int m = 0; m < MI; m++) {                                         \
        const bool e = (id == m);                                            \
        cw[m] += (unsigned)__popcll(__ballot(e));    /* scalar pipe */       \
        al[m] += e ? l : 0.f;                                                \
      }                                                                      \
    }
    SLOTP(x, x) SLOTP(y, y) SLOTP(z, z) SLOTP(w, w)
#undef SLOTP
  }

#pragma unroll
  for (int v = 0; v < 16; v++) red[wv][lane][v] = al[v];
  if (lane == 0) {
#pragma unroll
    for (int m = 0; m < MI; m++) cbuf[wv][m] = (float)cw[m];
  }
  __syncthreads();
  if (tid < 32) {
    const int m = tid >> 1, c = tid & 1;
    float s = 0.f;
    if (c == 0) {
#pragma unroll
      for (int w = 0; w < 4; w++)
#pragma unroll 8
        for (int l = 0; l < 64; l++) s += red[w][(l + tid) & 63][m];
    } else {
      s = cbuf[0][m] + cbuf[1][m] + cbuf[2][m] + cbuf[3][m];
    }
    ws[WS_PP + (size_t)(b * GPB + blk) * 32 + tid] = s;   // contiguous per block
  }
}

__global__ void k_final(const float* __restrict__ ws, float* __restrict__ out) {
  __shared__ float part[8][32];
  __shared__ float tot[32];
  const int b = blockIdx.x, t = threadIdx.x;   // 256 threads, one block per b
  const int v = t & 31, h = t >> 5;            // 8 chunks of 25 blocks
  float s = 0.f;
  const float* src = ws + WS_PP + (size_t)(b * GPB + h * 25) * 32 + v;
#pragma unroll 5
  for (int k = 0; k < 25; k++) s += src[(size_t)k * 32];
  part[h][v] = s;
  __syncthreads();
  if (t < 32) {
    float x = 0.f;
#pragma unroll
    for (int hh = 0; hh < 8; hh++) x += part[hh][t];
    tot[t] = x;
  }
  __syncthreads();
  if (t == 0) {
    const float* G = ws + WS_G;
    const float* valid = ws + WS_VAL;
    float nv = 0.f;
    for (int m = 0; m < MI; m++) nv += valid[b * MI + m];
    float pull = 0.f;
    for (int m = 0; m < MI; m++) {
      const float per = tot[m * 2] / fmaxf(tot[m * 2 + 1], 1.f);
      pull += per * valid[b * MI + m];
    }
    pull /= fmaxf(nv, 1.f);
    float push = 0.f;
    for (int i = 0; i < MI; i++) {
      if (valid[b * MI + i] == 0.f) continue;
      for (int j = i + 1; j < MI; j++) {
        if (valid[b * MI + j] == 0.f) continue;
        float d2 = CEPS;
        for (int c = 0; c < 4; c++) {
          const float df = G[(b * MI + i) * 4 + c] - G[(b * MI + j) * 4 + c];
          d2 += df * df;
        }
        const float dk = sqrtf(d2);
        const float tt = fmaxf(3.f - dk, 0.f);
        push += log1pf(tt * tt);
      }
    }
    const float denom = nv * (nv - 1.f);
    push = (nv > 1.f) ? push / fmaxf(denom, 1.f) : 0.f;
    out[b] = pull;
    out[BB + b] = push;
  }
}

extern "C" void kernel_launch(void* const* d_in, const int* in_sizes, int n_in,
                              void* d_out, int out_size, void* d_ws, size_t ws_size,
                              hipStream_t stream) {
  const float* outputs = (const float*)d_in[0];
  const int* gt_texts = (const int*)d_in[1];
  const int* gt_kernels = (const int*)d_in[2];
  float* ws = (float*)d_ws;
  float* out = (float*)d_out;

  dim3 grid(GPB, BB);
  k_sums<<<grid, TPB, 0, stream>>>(outputs, gt_kernels, ws);
  k_finG<<<BB, 400, 0, stream>>>(ws);
  k_pull<<<grid, TPB, 0, stream>>>(outputs, gt_texts, ws);
  k_final<<<BB, 256, 0, stream>>>(ws, out);
}